// Round 18
// baseline (42.061 us; speedup 1.0000x reference)
//
#include <hip/hip_runtime.h>
#include <hip/hip_bf16.h>
#include <stdint.h>

static constexpr int P_N   = 16384;
static constexpr int D_Z   = 512;
static constexpr int D_PHI = 256;
static constexpr int D_R   = 64;
static constexpr int H     = 96;    // H1 == H2
static constexpr int KP    = 832;   // 3*D_PHI + D_R

using f32x4 = __attribute__((ext_vector_type(4))) float;
using s16x8 = __attribute__((ext_vector_type(8))) short;

__device__ __forceinline__ unsigned short f2bf(float f) {
    union { float f; uint32_t u; } v; v.f = f;
    return (unsigned short)((v.u + 0x7FFFu + ((v.u >> 16) & 1u)) >> 16);
}

// packed RNE f32x2 -> bf16x2 (v_cvt_pk_bf16_f32)
__device__ __forceinline__ uint32_t pkbf2(float lo, float hi) {
    union { __hip_bfloat162 h; uint32_t u; } c;
    c.h = __float22bfloat162_rn(make_float2(lo, hi));
    return c.u;
}

// gelu(x) ~= x * sigmoid(1.5957691*(x + 0.044715 x^3))
//         =  x * rcp(1 + exp2(x*(-2.3022126 - 0.1029444 x^2)))
__device__ __forceinline__ float gelu_f(float x) {
    float x2 = x * x;
    float u  = __builtin_fmaf(-0.1029444f, x2, -2.3022126f);
    float e  = __builtin_amdgcn_exp2f(x * u);
    return x * __builtin_amdgcn_rcpf(1.0f + e);
}

// ---------------------------------------------------------------------------
// prep: fragment-contiguous weight layouts so every consumer B-load is
//       base + lane*16B (fully coalesced).
// ---------------------------------------------------------------------------
__global__ __launch_bounds__(256) void prep_kernel(
    const float* __restrict__ g_q, const float* __restrict__ W1,
    const float* __restrict__ b1, const float* __restrict__ W2,
    float* __restrict__ gqfrag, unsigned short* __restrict__ W1frag,
    unsigned short* __restrict__ W2frag)
{
    __shared__ float gql[D_Z];
    __shared__ float red[192];
    const int blk = blockIdx.x;
    const int t = threadIdx.x;
    if (blk < 16) {
        const int b = blk;
        for (int i = t; i < D_Z; i += 256) gql[i] = g_q[b * D_Z + i];
        __syncthreads();
        float acc = 0.f;
        if (t < 192) {
            const int n = t % 96, s = t / 96;
            const int k0 = s * 256;
            #pragma unroll 8
            for (int k = 0; k < 256; ++k)
                acc += gql[k0 + k] * W1[(k0 + k) * H + n];
            red[t] = acc;
        }
        __syncthreads();
        if (t < 96) {
            const float v = red[t] + red[t + 96] + b1[t];
            const int dst = ((t >> 5) * 64 + ((t >> 3) & 3) * 16 + b) * 8 + (t & 7);
            gqfrag[dst] = v;
        }
    } else if (blk < 328) {
        const int e = (blk - 16) * 256 + t;           // < 96*832
        const int n = e / KP, k = e % KP;
        const int nf = n >> 4, lr = n & 15;
        const int kc = k >> 5, l4 = (k >> 3) & 3, ke = k & 7;
        W1frag[((nf * 26 + kc) * 64 + l4 * 16 + lr) * 8 + ke] =
            f2bf(W1[(D_Z + k) * H + n]);
    } else {
        const int e = (blk - 328) * 256 + t;          // < 96*96
        const int n = e / H, k = e % H;
        const int nf = n >> 4, lr = n & 15;
        const int ks = k >> 5, l4 = (k >> 3) & 3, ke = k & 7;
        W2frag[((nf * 3 + ks) * 64 + l4 * 16 + lr) * 8 + ke] =
            f2bf(W2[k * H + n]);
    }
}

// ---------------------------------------------------------------------------
// fused16: fused15 + hoisted loop-invariant loads + setprio around MFMA.
//  32 pairs x 16 b per 512-thr block (8 waves), grid 512.
//  ph0 : 2 Phi-chunk tasks/thread (sum+|diff|+prod share one load pair)
//        -> feats[32][840] bf16; t<256 also copy rel chunks.
//  ph1 : waves 0..5 = (kh=w&1, ng=w>>1): 2 m-frags x 2 n-frags x 13 kc;
//        each B-load feeds 4 MFMA; partials -> y1part[kh][32][100].
//  ph2 : wave w -> pairs 4w..4w+3; gq / b2 / W3 hoisted to registers
//        before the loop; per mf: afr[3] -> 18 MFMA vs W2frag -> gelu ->
//        dot W3 -> shfl-reduce -> store.
//  LDS 79.4KB -> 2 blocks/CU.
// ---------------------------------------------------------------------------
__global__ __launch_bounds__(512, 2) void fused16_kernel(
    const float* __restrict__ Phi, const int* __restrict__ pidx,
    const float* __restrict__ rel, const unsigned short* __restrict__ W1frag,
    const float* __restrict__ gqfrag, const unsigned short* __restrict__ W2frag,
    const float* __restrict__ b2, const float* __restrict__ W3,
    const float* __restrict__ b3, float* __restrict__ out)
{
    constexpr int FS = 840;                       // feats stride (shorts)
    __shared__ __align__(16) unsigned short feats[32 * FS];   // 53760 B
    __shared__ __align__(16) float y1part[2][32][100];        // 25600 B
    const int t = threadIdx.x;
    const int p0 = blockIdx.x * 32;

    // phase 0: 32 pairs x 32 chunks (2 tasks/thread); shared-load build
    #pragma unroll
    for (int it = 0; it < 2; ++it) {
        const int task = t + it * 512;
        const int p = task >> 5, c = task & 31, kb = c * 8;
        const int2 ij = *(const int2*)(pidx + 2 * (p0 + p));
        const float* PI = Phi + (long)ij.x * D_PHI + kb;
        const float* PJ = Phi + (long)ij.y * D_PHI + kb;
        float4 a0 = *(const float4*)PI, a1 = *(const float4*)(PI + 4);
        float4 c0 = *(const float4*)PJ, c1 = *(const float4*)(PJ + 4);
        uint4 s, d, q;
        s.x = pkbf2(a0.x + c0.x, a0.y + c0.y);
        s.y = pkbf2(a0.z + c0.z, a0.w + c0.w);
        s.z = pkbf2(a1.x + c1.x, a1.y + c1.y);
        s.w = pkbf2(a1.z + c1.z, a1.w + c1.w);
        d.x = pkbf2(fabsf(a0.x - c0.x), fabsf(a0.y - c0.y));
        d.y = pkbf2(fabsf(a0.z - c0.z), fabsf(a0.w - c0.w));
        d.z = pkbf2(fabsf(a1.x - c1.x), fabsf(a1.y - c1.y));
        d.w = pkbf2(fabsf(a1.z - c1.z), fabsf(a1.w - c1.w));
        q.x = pkbf2(a0.x * c0.x, a0.y * c0.y);
        q.y = pkbf2(a0.z * c0.z, a0.w * c0.w);
        q.z = pkbf2(a1.x * c1.x, a1.y * c1.y);
        q.w = pkbf2(a1.z * c1.z, a1.w * c1.w);
        *(uint4*)&feats[p * FS + kb]       = s;
        *(uint4*)&feats[p * FS + 256 + kb] = d;
        *(uint4*)&feats[p * FS + 512 + kb] = q;
    }
    if (t < 256) {   // relation features: 32 pairs x 8 chunks
        const int p2 = t >> 3, c2 = t & 7;
        const float* R = rel + (long)(p0 + p2) * D_R + c2 * 8;
        float4 r0 = *(const float4*)R, r1 = *(const float4*)(R + 4);
        uint4 rr;
        rr.x = pkbf2(r0.x, r0.y); rr.y = pkbf2(r0.z, r0.w);
        rr.z = pkbf2(r1.x, r1.y); rr.w = pkbf2(r1.z, r1.w);
        *(uint4*)&feats[p2 * FS + 768 + c2 * 8] = rr;
    }
    __syncthreads();

    const int w  = t >> 6;
    const int l  = t & 63;
    const int lr = l & 15, l4 = l >> 4;

    // phase 1: waves 0..5: (kh, ng): 2 m-frags x 2 n-frags x 13 kc.
    if (w < 6) {
        const int kh = w & 1, ng = w >> 1;       // ng in {0,1,2}
        const int kc0 = kh * 13;
        f32x4 acc[2][2];
        #pragma unroll
        for (int m = 0; m < 2; ++m)
            #pragma unroll
            for (int j = 0; j < 2; ++j)
                acc[m][j] = (f32x4){0.f,0.f,0.f,0.f};
        const unsigned short* A0 = &feats[lr * FS + l4 * 8];
        const unsigned short* A1 = &feats[(16 + lr) * FS + l4 * 8];
        __builtin_amdgcn_s_setprio(1);
        for (int kc = kc0; kc < kc0 + 13; ++kc) {
            const s16x8 a0 = *(const s16x8*)(A0 + kc * 32);
            const s16x8 a1 = *(const s16x8*)(A1 + kc * 32);
            #pragma unroll
            for (int j = 0; j < 2; ++j) {
                const s16x8 bb = *(const s16x8*)(W1frag +
                    (((ng * 2 + j) * 26 + kc) * 64 + l) * 8);
                acc[0][j] = __builtin_amdgcn_mfma_f32_16x16x32_bf16(a0, bb, acc[0][j], 0, 0, 0);
                acc[1][j] = __builtin_amdgcn_mfma_f32_16x16x32_bf16(a1, bb, acc[1][j], 0, 0, 0);
            }
        }
        __builtin_amdgcn_s_setprio(0);
        #pragma unroll
        for (int m = 0; m < 2; ++m)
            #pragma unroll
            for (int j = 0; j < 2; ++j)
                #pragma unroll
                for (int r = 0; r < 4; ++r)
                    y1part[kh][m * 16 + l4 * 4 + r][ng * 32 + j * 16 + lr] = acc[m][j][r];
    }
    __syncthreads();

    // hoist loop-invariant values for ph2 (reused across 4 mf passes)
    float gq[3][8];
    #pragma unroll
    for (int ks = 0; ks < 3; ++ks) {
        const float* gp = gqfrag + (ks * 64 + l) * 8;
        float4 g0 = *(const float4*)gp, g1 = *(const float4*)(gp + 4);
        gq[ks][0]=g0.x; gq[ks][1]=g0.y; gq[ks][2]=g0.z; gq[ks][3]=g0.w;
        gq[ks][4]=g1.x; gq[ks][5]=g1.y; gq[ks][6]=g1.z; gq[ks][7]=g1.w;
    }
    float b2v[6], w3v[6];
    #pragma unroll
    for (int nf = 0; nf < 6; ++nf) {
        b2v[nf] = b2[nf * 16 + lr];
        w3v[nf] = W3[nf * 16 + lr];
    }
    const float b3v = b3[0];

    // phase 2: pairs 4w..4w+3, one mf at a time; reduce+store per pass
    #pragma unroll
    for (int mf = 0; mf < 4; ++mf) {
        const int pl = 4 * w + mf;

        // 2a: A-fragments in consumer layout (row lr = b); sum 2 partials
        s16x8 afr[3];
        #pragma unroll
        for (int ks = 0; ks < 3; ++ks) {
            const int c = ks * 32 + l4 * 8;
            const float* ya = &y1part[0][pl][c];    // broadcast reads
            const float* yb = &y1part[1][pl][c];
            float4 u0 = *(const float4*)ya, u1 = *(const float4*)(ya + 4);
            float4 v0 = *(const float4*)yb, v1 = *(const float4*)(yb + 4);
            union { s16x8 v; uint32_t u[4]; } pk;
            pk.u[0] = pkbf2(gelu_f(gq[ks][0] + u0.x + v0.x), gelu_f(gq[ks][1] + u0.y + v0.y));
            pk.u[1] = pkbf2(gelu_f(gq[ks][2] + u0.z + v0.z), gelu_f(gq[ks][3] + u0.w + v0.w));
            pk.u[2] = pkbf2(gelu_f(gq[ks][4] + u1.x + v1.x), gelu_f(gq[ks][5] + u1.y + v1.y));
            pk.u[3] = pkbf2(gelu_f(gq[ks][6] + u1.z + v1.z), gelu_f(gq[ks][7] + u1.w + v1.w));
            afr[ks] = pk.v;
        }

        // 2b: layer-2 MFMA vs W2frag (L1-hot), acc init = b2
        f32x4 acc2[6];
        #pragma unroll
        for (int nf = 0; nf < 6; ++nf)
            acc2[nf] = (f32x4){b2v[nf], b2v[nf], b2v[nf], b2v[nf]};
        __builtin_amdgcn_s_setprio(1);
        #pragma unroll
        for (int ks = 0; ks < 3; ++ks) {
            #pragma unroll
            for (int nf = 0; nf < 6; ++nf) {
                const s16x8 bb = *(const s16x8*)(W2frag + ((nf * 3 + ks) * 64 + l) * 8);
                acc2[nf] = __builtin_amdgcn_mfma_f32_16x16x32_bf16(afr[ks], bb, acc2[nf], 0, 0, 0);
            }
        }
        __builtin_amdgcn_s_setprio(0);

        // 2c: gelu -> dot W3 -> reduce over 16 col-lanes -> store
        float part[4] = {0.f, 0.f, 0.f, 0.f};
        #pragma unroll
        for (int nf = 0; nf < 6; ++nf) {
            #pragma unroll
            for (int r4 = 0; r4 < 4; ++r4)
                part[r4] = __builtin_fmaf(gelu_f(acc2[nf][r4]), w3v[nf], part[r4]);
        }
        #pragma unroll
        for (int mask = 1; mask <= 8; mask <<= 1)
            #pragma unroll
            for (int r4 = 0; r4 < 4; ++r4)
                part[r4] += __shfl_xor(part[r4], mask, 64);
        if (lr == 0) {
            #pragma unroll
            for (int r4 = 0; r4 < 4; ++r4)
                out[(l4 * 4 + r4) * P_N + p0 + pl] = part[r4] + b3v;
        }
    }
}

extern "C" void kernel_launch(void* const* d_in, const int* in_sizes, int n_in,
                              void* d_out, int out_size, void* d_ws, size_t ws_size,
                              hipStream_t stream)
{
    const float* g_q  = (const float*)d_in[0];
    const float* Phi  = (const float*)d_in[1];
    const int*   pidx = (const int*)d_in[2];
    const float* rel  = (const float*)d_in[3];
    const float* W1   = (const float*)d_in[4];
    const float* b1   = (const float*)d_in[5];
    const float* W2   = (const float*)d_in[6];
    const float* b2   = (const float*)d_in[7];
    const float* W3   = (const float*)d_in[8];
    const float* b3   = (const float*)d_in[9];
    float* out = (float*)d_out;

    char* ws = (char*)d_ws;
    float*          gqfrag = (float*)(ws + 0);               // 3*64*8 f32 = 6KB
    unsigned short* W1frag = (unsigned short*)(ws + 8192);   // 96*832*2
    unsigned short* W2frag = (unsigned short*)(ws + 167936); // 96*96*2

    hipLaunchKernelGGL(prep_kernel, dim3(364), dim3(256), 0, stream,
                       g_q, W1, b1, W2, gqfrag, W1frag, W2frag);
    hipLaunchKernelGGL(fused16_kernel, dim3(P_N / 32), dim3(512), 0, stream,
                       Phi, pidx, rel, W1frag, gqfrag, W2frag, b2, W3, b3, out);
}

// Round 19
// 37.947 us; speedup vs baseline: 1.1084x; 1.1084x over previous
//
#include <hip/hip_runtime.h>
#include <hip/hip_bf16.h>
#include <stdint.h>

static constexpr int P_N   = 16384;
static constexpr int D_Z   = 512;
static constexpr int D_PHI = 256;
static constexpr int D_R   = 64;
static constexpr int H     = 96;    // H1 == H2
static constexpr int KP    = 832;   // 3*D_PHI + D_R

using f32x4 = __attribute__((ext_vector_type(4))) float;
using s16x8 = __attribute__((ext_vector_type(8))) short;

__device__ __forceinline__ unsigned short f2bf(float f) {
    union { float f; uint32_t u; } v; v.f = f;
    return (unsigned short)((v.u + 0x7FFFu + ((v.u >> 16) & 1u)) >> 16);
}

// packed RNE f32x2 -> bf16x2 (v_cvt_pk_bf16_f32)
__device__ __forceinline__ uint32_t pkbf2(float lo, float hi) {
    union { __hip_bfloat162 h; uint32_t u; } c;
    c.h = __float22bfloat162_rn(make_float2(lo, hi));
    return c.u;
}

// gelu(x) ~= x * sigmoid(1.5957691*(x + 0.044715 x^3))
//         =  x * rcp(1 + exp2(x*(-2.3022126 - 0.1029444 x^2)))
__device__ __forceinline__ float gelu_f(float x) {
    float x2 = x * x;
    float u  = __builtin_fmaf(-0.1029444f, x2, -2.3022126f);
    float e  = __builtin_amdgcn_exp2f(x * u);
    return x * __builtin_amdgcn_rcpf(1.0f + e);
}

// ---------------------------------------------------------------------------
// prep: fragment-contiguous weight layouts so every consumer B-load is
//       base + lane*16B (fully coalesced).
// ---------------------------------------------------------------------------
__global__ __launch_bounds__(256) void prep_kernel(
    const float* __restrict__ g_q, const float* __restrict__ W1,
    const float* __restrict__ b1, const float* __restrict__ W2,
    float* __restrict__ gqfrag, unsigned short* __restrict__ W1frag,
    unsigned short* __restrict__ W2frag)
{
    __shared__ float gql[D_Z];
    __shared__ float red[192];
    const int blk = blockIdx.x;
    const int t = threadIdx.x;
    if (blk < 16) {
        const int b = blk;
        for (int i = t; i < D_Z; i += 256) gql[i] = g_q[b * D_Z + i];
        __syncthreads();
        float acc = 0.f;
        if (t < 192) {
            const int n = t % 96, s = t / 96;
            const int k0 = s * 256;
            #pragma unroll 8
            for (int k = 0; k < 256; ++k)
                acc += gql[k0 + k] * W1[(k0 + k) * H + n];
            red[t] = acc;
        }
        __syncthreads();
        if (t < 96) {
            const float v = red[t] + red[t + 96] + b1[t];
            const int dst = ((t >> 5) * 64 + ((t >> 3) & 3) * 16 + b) * 8 + (t & 7);
            gqfrag[dst] = v;
        }
    } else if (blk < 328) {
        const int e = (blk - 16) * 256 + t;           // < 96*832
        const int n = e / KP, k = e % KP;
        const int nf = n >> 4, lr = n & 15;
        const int kc = k >> 5, l4 = (k >> 3) & 3, ke = k & 7;
        W1frag[((nf * 26 + kc) * 64 + l4 * 16 + lr) * 8 + ke] =
            f2bf(W1[(D_Z + k) * H + n]);
    } else {
        const int e = (blk - 328) * 256 + t;          // < 96*96
        const int n = e / H, k = e % H;
        const int nf = n >> 4, lr = n & 15;
        const int ks = k >> 5, l4 = (k >> 3) & 3, ke = k & 7;
        W2frag[((nf * 3 + ks) * 64 + l4 * 16 + lr) * 8 + ke] =
            f2bf(W2[k * H + n]);
    }
}

// ---------------------------------------------------------------------------
// fused15: 32 pairs x 16 b per 512-thr block (8 waves), grid 512.
//  ph0 : 2 Phi-chunk tasks per thread (sum+|diff|+prod share one load pair)
//        -> feats[32][840] bf16; t<256 also copy rel chunks.
//  ph1 : waves 0..5 = (kh=w&1, ng=w>>1): 2 m-frags x 2 n-frags x 13 kc;
//        each B-load feeds 4 MFMA (2x arithmetic intensity vs fused11);
//        partials -> y1part[kh][32][100].  Waves 6,7 idle (short phase).
//  ph2 : wave w -> pairs 4w..4w+3; per mf: afr[3] -> 18 MFMA vs W2frag ->
//        gelu -> dot W3 -> shfl-reduce -> store (reduce folded per pass).
//  LDS 79.4KB -> 2 blocks/CU (same as the 68-VGPR wave cap).
// ---------------------------------------------------------------------------
__global__ __launch_bounds__(512, 2) void fused15_kernel(
    const float* __restrict__ Phi, const int* __restrict__ pidx,
    const float* __restrict__ rel, const unsigned short* __restrict__ W1frag,
    const float* __restrict__ gqfrag, const unsigned short* __restrict__ W2frag,
    const float* __restrict__ b2, const float* __restrict__ W3,
    const float* __restrict__ b3, float* __restrict__ out)
{
    constexpr int FS = 840;                       // feats stride (shorts)
    __shared__ __align__(16) unsigned short feats[32 * FS];   // 53760 B
    __shared__ __align__(16) float y1part[2][32][100];        // 25600 B
    const int t = threadIdx.x;
    const int p0 = blockIdx.x * 32;

    // phase 0: 32 pairs x 32 chunks (2 tasks/thread); shared-load build
    #pragma unroll
    for (int it = 0; it < 2; ++it) {
        const int task = t + it * 512;
        const int p = task >> 5, c = task & 31, kb = c * 8;
        const int2 ij = *(const int2*)(pidx + 2 * (p0 + p));
        const float* PI = Phi + (long)ij.x * D_PHI + kb;
        const float* PJ = Phi + (long)ij.y * D_PHI + kb;
        float4 a0 = *(const float4*)PI, a1 = *(const float4*)(PI + 4);
        float4 c0 = *(const float4*)PJ, c1 = *(const float4*)(PJ + 4);
        uint4 s, d, q;
        s.x = pkbf2(a0.x + c0.x, a0.y + c0.y);
        s.y = pkbf2(a0.z + c0.z, a0.w + c0.w);
        s.z = pkbf2(a1.x + c1.x, a1.y + c1.y);
        s.w = pkbf2(a1.z + c1.z, a1.w + c1.w);
        d.x = pkbf2(fabsf(a0.x - c0.x), fabsf(a0.y - c0.y));
        d.y = pkbf2(fabsf(a0.z - c0.z), fabsf(a0.w - c0.w));
        d.z = pkbf2(fabsf(a1.x - c1.x), fabsf(a1.y - c1.y));
        d.w = pkbf2(fabsf(a1.z - c1.z), fabsf(a1.w - c1.w));
        q.x = pkbf2(a0.x * c0.x, a0.y * c0.y);
        q.y = pkbf2(a0.z * c0.z, a0.w * c0.w);
        q.z = pkbf2(a1.x * c1.x, a1.y * c1.y);
        q.w = pkbf2(a1.z * c1.z, a1.w * c1.w);
        *(uint4*)&feats[p * FS + kb]       = s;
        *(uint4*)&feats[p * FS + 256 + kb] = d;
        *(uint4*)&feats[p * FS + 512 + kb] = q;
    }
    if (t < 256) {   // relation features: 32 pairs x 8 chunks
        const int p2 = t >> 3, c2 = t & 7;
        const float* R = rel + (long)(p0 + p2) * D_R + c2 * 8;
        float4 r0 = *(const float4*)R, r1 = *(const float4*)(R + 4);
        uint4 rr;
        rr.x = pkbf2(r0.x, r0.y); rr.y = pkbf2(r0.z, r0.w);
        rr.z = pkbf2(r1.x, r1.y); rr.w = pkbf2(r1.z, r1.w);
        *(uint4*)&feats[p2 * FS + 768 + c2 * 8] = rr;
    }
    __syncthreads();

    const int w  = t >> 6;
    const int l  = t & 63;
    const int lr = l & 15, l4 = l >> 4;

    // phase 1: waves 0..5: (kh, ng): 2 m-frags x 2 n-frags x 13 kc.
    //          B loaded once per (j,kc), reused for both m-frags.
    if (w < 6) {
        const int kh = w & 1, ng = w >> 1;       // ng in {0,1,2}
        const int kc0 = kh * 13;
        f32x4 acc[2][2];
        #pragma unroll
        for (int m = 0; m < 2; ++m)
            #pragma unroll
            for (int j = 0; j < 2; ++j)
                acc[m][j] = (f32x4){0.f,0.f,0.f,0.f};
        const unsigned short* A0 = &feats[lr * FS + l4 * 8];
        const unsigned short* A1 = &feats[(16 + lr) * FS + l4 * 8];
        for (int kc = kc0; kc < kc0 + 13; ++kc) {
            const s16x8 a0 = *(const s16x8*)(A0 + kc * 32);
            const s16x8 a1 = *(const s16x8*)(A1 + kc * 32);
            #pragma unroll
            for (int j = 0; j < 2; ++j) {
                const s16x8 bb = *(const s16x8*)(W1frag +
                    (((ng * 2 + j) * 26 + kc) * 64 + l) * 8);
                acc[0][j] = __builtin_amdgcn_mfma_f32_16x16x32_bf16(a0, bb, acc[0][j], 0, 0, 0);
                acc[1][j] = __builtin_amdgcn_mfma_f32_16x16x32_bf16(a1, bb, acc[1][j], 0, 0, 0);
            }
        }
        #pragma unroll
        for (int m = 0; m < 2; ++m)
            #pragma unroll
            for (int j = 0; j < 2; ++j)
                #pragma unroll
                for (int r = 0; r < 4; ++r)
                    y1part[kh][m * 16 + l4 * 4 + r][ng * 32 + j * 16 + lr] = acc[m][j][r];
    }
    __syncthreads();

    // phase 2: pairs 4w..4w+3, one mf at a time; reduce+store per pass
    const float b3v = b3[0];
    #pragma unroll
    for (int mf = 0; mf < 4; ++mf) {
        const int pl = 4 * w + mf;

        // 2a: A-fragments in consumer layout (row lr = b); sum 2 partials
        s16x8 afr[3];
        #pragma unroll
        for (int ks = 0; ks < 3; ++ks) {
            const int c = ks * 32 + l4 * 8;
            const float* gp = gqfrag + (ks * 64 + l) * 8;
            float4 g0 = *(const float4*)gp, g1 = *(const float4*)(gp + 4);
            const float* ya = &y1part[0][pl][c];    // broadcast reads
            const float* yb = &y1part[1][pl][c];
            float4 u0 = *(const float4*)ya, u1 = *(const float4*)(ya + 4);
            float4 v0 = *(const float4*)yb, v1 = *(const float4*)(yb + 4);
            union { s16x8 v; uint32_t u[4]; } pk;
            pk.u[0] = pkbf2(gelu_f(g0.x + u0.x + v0.x), gelu_f(g0.y + u0.y + v0.y));
            pk.u[1] = pkbf2(gelu_f(g0.z + u0.z + v0.z), gelu_f(g0.w + u0.w + v0.w));
            pk.u[2] = pkbf2(gelu_f(g1.x + u1.x + v1.x), gelu_f(g1.y + u1.y + v1.y));
            pk.u[3] = pkbf2(gelu_f(g1.z + u1.z + v1.z), gelu_f(g1.w + u1.w + v1.w));
            afr[ks] = pk.v;
        }

        // 2b: layer-2 MFMA vs W2frag (L1-hot), acc init = b2
        f32x4 acc2[6];
        #pragma unroll
        for (int nf = 0; nf < 6; ++nf) {
            const float bv = b2[nf * 16 + lr];
            acc2[nf] = (f32x4){bv, bv, bv, bv};
        }
        #pragma unroll
        for (int ks = 0; ks < 3; ++ks) {
            #pragma unroll
            for (int nf = 0; nf < 6; ++nf) {
                const s16x8 bb = *(const s16x8*)(W2frag + ((nf * 3 + ks) * 64 + l) * 8);
                acc2[nf] = __builtin_amdgcn_mfma_f32_16x16x32_bf16(afr[ks], bb, acc2[nf], 0, 0, 0);
            }
        }

        // 2c: gelu -> dot W3 -> reduce over 16 col-lanes -> store
        float part[4] = {0.f, 0.f, 0.f, 0.f};
        #pragma unroll
        for (int nf = 0; nf < 6; ++nf) {
            const float wv = W3[nf * 16 + lr];
            #pragma unroll
            for (int r4 = 0; r4 < 4; ++r4)
                part[r4] = __builtin_fmaf(gelu_f(acc2[nf][r4]), wv, part[r4]);
        }
        #pragma unroll
        for (int mask = 1; mask <= 8; mask <<= 1)
            #pragma unroll
            for (int r4 = 0; r4 < 4; ++r4)
                part[r4] += __shfl_xor(part[r4], mask, 64);
        if (lr == 0) {
            #pragma unroll
            for (int r4 = 0; r4 < 4; ++r4)
                out[(l4 * 4 + r4) * P_N + p0 + pl] = part[r4] + b3v;
        }
    }
}

extern "C" void kernel_launch(void* const* d_in, const int* in_sizes, int n_in,
                              void* d_out, int out_size, void* d_ws, size_t ws_size,
                              hipStream_t stream)
{
    const float* g_q  = (const float*)d_in[0];
    const float* Phi  = (const float*)d_in[1];
    const int*   pidx = (const int*)d_in[2];
    const float* rel  = (const float*)d_in[3];
    const float* W1   = (const float*)d_in[4];
    const float* b1   = (const float*)d_in[5];
    const float* W2   = (const float*)d_in[6];
    const float* b2   = (const float*)d_in[7];
    const float* W3   = (const float*)d_in[8];
    const float* b3   = (const float*)d_in[9];
    float* out = (float*)d_out;

    char* ws = (char*)d_ws;
    float*          gqfrag = (float*)(ws + 0);               // 3*64*8 f32 = 6KB
    unsigned short* W1frag = (unsigned short*)(ws + 8192);   // 96*832*2
    unsigned short* W2frag = (unsigned short*)(ws + 167936); // 96*96*2

    hipLaunchKernelGGL(prep_kernel, dim3(364), dim3(256), 0, stream,
                       g_q, W1, b1, W2, gqfrag, W1frag, W2frag);
    hipLaunchKernelGGL(fused15_kernel, dim3(P_N / 32), dim3(512), 0, stream,
                       Phi, pidx, rel, W1frag, gqfrag, W2frag, b2, W3, b3, out);
}